// Round 1
// baseline (110.436 us; speedup 1.0000x reference)
//
#include <hip/hip_runtime.h>
#include <math.h>

// Problem constants
constexpr int B = 1024;
constexpr int IN = 512;
constexpr int HID = 256;

// Gumbel-perturbed score. Forward of gumbel-hard-select == one_hot(argmax(logits + g)).
__device__ __forceinline__ float gumbel_score(float logit, float u) {
    float uc = fminf(fmaxf(u, 1e-10f), 1.0f);
    return logit - logf(-logf(uc));
}

// Build the (w, z) coefficient tables, transposed to [j][row] so that lanes
// (which span the output-row dim) load them coalesced.
// Inner op everywhere: acc = min(acc, fma(w, x, z)).
//   min row (choose=0): masked -> (1,0), unmasked -> (0,1)   ; init 1.0
//   max row (choose=1, negated domain): masked -> (-1,0), unmasked -> (0,0) ; init 0.0
__global__ void prep_kernel(const float* __restrict__ logits1, const float* __restrict__ u1,
                            const float* __restrict__ logits2, const float* __restrict__ u2,
                            const int* __restrict__ mask1, const int* __restrict__ mask2,
                            float2* __restrict__ wz1, float2* __restrict__ wz2)
{
    int idx = blockIdx.x * blockDim.x + threadIdx.x;
    constexpr int N1 = IN * HID;  // 131072 (j in [0,512), i in [0,256))
    if (idx < N1) {
        int i = idx & (HID - 1);
        int j = idx >> 8;
        float s0 = gumbel_score(logits1[2 * i], u1[2 * i]);
        float s1 = gumbel_score(logits1[2 * i + 1], u1[2 * i + 1]);
        bool mx = s1 > s0;
        bool m = mask1[i * IN + j] != 0;
        float w = m ? (mx ? -1.0f : 1.0f) : 0.0f;
        float z = (!m && !mx) ? 1.0f : 0.0f;
        wz1[idx] = make_float2(w, z);
    } else {
        int e = idx - N1;
        constexpr int N2 = HID * IN;  // 131072 (j in [0,256), o in [0,512))
        if (e < N2) {
            int o = e & (IN - 1);
            int j = e >> 9;
            float s0 = gumbel_score(logits2[2 * o], u2[2 * o]);
            float s1 = gumbel_score(logits2[2 * o + 1], u2[2 * o + 1]);
            bool mx = s1 > s0;
            bool m = mask2[o * HID + j] != 0;  // mask2 shape (512, 256) indexed [o][j]
            float w = m ? (mx ? -1.0f : 1.0f) : 0.0f;
            float z = (!m && !mx) ? 1.0f : 0.0f;
            wz2[e] = make_float2(w, z);
        }
    }
}

// One layer, j-split into JSPLIT partial reductions written to `part`.
// Block = 256 threads = 4 waves. Lanes span 64 output rows (coalesced wz load +
// coalesced partial store). Each wave owns 8 batch rows (wave-uniform -> x loads
// are scalar-promotable). Each thread register-tiles those 8 batch accumulators.
template <int JD, int OD, int JSPLIT>
__global__ __launch_bounds__(256) void layer_kernel(
    const float* __restrict__ xin,      // [B, JD]
    const float2* __restrict__ wzT,     // [JD, OD]
    const float* __restrict__ logits,   // [OD, 2]
    const float* __restrict__ u,        // [OD, 2]
    float* __restrict__ part)           // [JSPLIT, B, OD]
{
    constexpr int JLEN = JD / JSPLIT;
    constexpr int OTILES = OD / 64;

    int bx = blockIdx.x;
    int btile = bx & 31;       // 32 batch tiles of 32
    int rest = bx >> 5;
    int otile = rest % OTILES;
    int jq = rest / OTILES;

    int lane = threadIdx.x & 63;
    int wv = __builtin_amdgcn_readfirstlane((int)(threadIdx.x >> 6));
    int o = otile * 64 + lane;
    int b0 = btile * 32 + wv * 8;
    int j0 = jq * JLEN;

    // Row type (per lane, branchless)
    float s0 = gumbel_score(logits[2 * o], u[2 * o]);
    float s1 = gumbel_score(logits[2 * o + 1], u[2 * o + 1]);
    bool mx = s1 > s0;
    float ini = mx ? 0.0f : 1.0f;

    float acc[8];
#pragma unroll
    for (int bb = 0; bb < 8; ++bb) acc[bb] = ini;

    const float2* wp = wzT + (size_t)j0 * OD + o;
    const float* xbase = xin + (size_t)b0 * JD + j0;

    for (int j = 0; j < JLEN; j += 4) {
        float2 wz0 = wp[(size_t)(j + 0) * OD];
        float2 wz1 = wp[(size_t)(j + 1) * OD];
        float2 wz2 = wp[(size_t)(j + 2) * OD];
        float2 wz3 = wp[(size_t)(j + 3) * OD];
#pragma unroll
        for (int bb = 0; bb < 8; ++bb) {
            const float4 xv = *reinterpret_cast<const float4*>(xbase + (size_t)bb * JD + j);
            float a = acc[bb];
            a = fminf(a, fmaf(wz0.x, xv.x, wz0.y));
            a = fminf(a, fmaf(wz1.x, xv.y, wz1.y));
            a = fminf(a, fmaf(wz2.x, xv.z, wz2.y));
            a = fminf(a, fmaf(wz3.x, xv.w, wz3.y));
            acc[bb] = a;
        }
    }

#pragma unroll
    for (int bb = 0; bb < 8; ++bb) {
        part[((size_t)jq * B + (b0 + bb)) * OD + o] = acc[bb];
    }
}

// Combine 4 layer-1 partials, undo the negation for max rows.
__global__ void combine1_kernel(const float* __restrict__ part, float* __restrict__ h,
                                const float* __restrict__ logits1, const float* __restrict__ u1)
{
    constexpr int N = B * HID;  // 262144
    int idx = blockIdx.x * blockDim.x + threadIdx.x;
    if (idx >= N) return;
    int i = idx & (HID - 1);
    float v = fminf(fminf(part[idx], part[N + idx]),
                    fminf(part[2 * (size_t)N + idx], part[3 * (size_t)N + idx]));
    float s0 = gumbel_score(logits1[2 * i], u1[2 * i]);
    float s1 = gumbel_score(logits1[2 * i + 1], u1[2 * i + 1]);
    bool mx = s1 > s0;
    h[idx] = mx ? -v : v;
}

// Combine 2 layer-2 partials, undo negation, write final output.
__global__ void combine2_kernel(const float* __restrict__ part, float* __restrict__ out,
                                const float* __restrict__ logits2, const float* __restrict__ u2)
{
    constexpr int N = B * IN;  // 524288
    int idx = blockIdx.x * blockDim.x + threadIdx.x;
    if (idx >= N) return;
    int o = idx & (IN - 1);
    float v = fminf(part[idx], part[(size_t)N + idx]);
    float s0 = gumbel_score(logits2[2 * o], u2[2 * o]);
    float s1 = gumbel_score(logits2[2 * o + 1], u2[2 * o + 1]);
    bool mx = s1 > s0;
    out[idx] = mx ? -v : v;
}

extern "C" void kernel_launch(void* const* d_in, const int* in_sizes, int n_in,
                              void* d_out, int out_size, void* d_ws, size_t ws_size,
                              hipStream_t stream)
{
    const float* x       = (const float*)d_in[0];  // (1024, 512)
    const float* logits1 = (const float*)d_in[1];  // (256, 2)
    const float* u1      = (const float*)d_in[2];  // (256, 2)
    const float* logits2 = (const float*)d_in[3];  // (512, 2)
    const float* u2      = (const float*)d_in[4];  // (512, 2)
    const int*   mask1   = (const int*)d_in[5];    // (256, 512) bool as int32
    const int*   mask2   = (const int*)d_in[6];    // (512, 256) bool as int32
    float* out = (float*)d_out;                    // (1024, 512)

    char* ws = (char*)d_ws;
    float2* wz1  = (float2*)(ws);                        // 1 MB: [512][256] (w,z)
    float2* wz2  = (float2*)(ws + (1 << 20));            // 1 MB: [256][512] (w,z)
    float*  h    = (float*)(ws + (2 << 20));             // 1 MB: [1024][256]
    float*  part = (float*)(ws + (3 << 20));             // 4 MB: partials (reused by both layers)

    // 1) Build coefficient tables (262144 elems)
    prep_kernel<<<1024, 256, 0, stream>>>(logits1, u1, logits2, u2, mask1, mask2, wz1, wz2);

    // 2) Layer 1: JD=512, OD=256, j split 4-way. Grid = 32 btiles * 4 otiles * 4 jq = 512
    layer_kernel<IN, HID, 4><<<512, 256, 0, stream>>>(x, wz1, logits1, u1, part);

    // 3) Combine layer-1 partials -> h
    combine1_kernel<<<1024, 256, 0, stream>>>(part, h, logits1, u1);

    // 4) Layer 2: JD=256, OD=512, j split 2-way. Grid = 32 * 8 * 2 = 512
    layer_kernel<HID, IN, 2><<<512, 256, 0, stream>>>(h, wz2, logits2, u2, part);

    // 5) Combine layer-2 partials -> out
    combine2_kernel<<<2048, 256, 0, stream>>>(part, out, logits2, u2);
}

// Round 2
// 103.270 us; speedup vs baseline: 1.0694x; 1.0694x over previous
//
#include <hip/hip_runtime.h>
#include <math.h>

// Problem constants
constexpr int B = 1024;
constexpr int IN = 512;
constexpr int HID = 256;

// Packed fp16 pair (maps to v_pk_* ops on gfx950)
typedef _Float16 h2 __attribute__((ext_vector_type(2)));

// (w,z) coefficient pair for two consecutive j's, 8 bytes.
// Inner op everywhere: acc2 = pk_min(acc2, pk_fma(w2, x2, z2)).
//   min row:            masked -> (1,0), unmasked -> (0,1) ; init 1.0
//   max row (negated):  masked -> (-1,0), unmasked -> (0,0); init 0.0, sign-fix at end
struct WZ { h2 w; h2 z; };

__device__ __forceinline__ float gscore(float l, float u) {
    float uc = fminf(fmaxf(u, 1e-10f), 1.0f);
    return l - logf(-logf(uc));
}
// true -> argmax is index 1 -> "max" node (strict >, matching jnp.argmax tie->0)
__device__ __forceinline__ bool rowmax(const float* __restrict__ lg,
                                       const float* __restrict__ uu, int r) {
    return gscore(lg[2 * r + 1], uu[2 * r + 1]) > gscore(lg[2 * r], uu[2 * r]);
}

// One prep kernel: pack x -> fp16 pairs, build both WZ tables (transposed to
// [j-pair][row] so layer-kernel lanes spanning the row dim load coalesced).
__global__ __launch_bounds__(256) void prep_kernel(
    const float* __restrict__ x,
    const float* __restrict__ lg1, const float* __restrict__ u1,
    const float* __restrict__ lg2, const float* __restrict__ u2,
    const int* __restrict__ m1, const int* __restrict__ m2,
    WZ* __restrict__ wz1, WZ* __restrict__ wz2, h2* __restrict__ xh)
{
    int idx = blockIdx.x * 256 + threadIdx.x;
    constexpr int NXH = B * IN / 2;        // 262144
    constexpr int NW1 = (IN / 2) * HID;    // 65536  [jp<256][i<256]
    if (idx < NXH) {
        float2 xv = reinterpret_cast<const float2*>(x)[idx];
        h2 hv;
        hv.x = (_Float16)xv.x;
        hv.y = (_Float16)xv.y;
        xh[idx] = hv;                      // xh[b][jp], jp = idx & 255
    } else if (idx < NXH + NW1) {
        int e = idx - NXH;
        int i = e & (HID - 1);
        int jp = e >> 8;
        bool mx = rowmax(lg1, u1, i);
        bool ma = m1[i * IN + 2 * jp] != 0;
        bool mb = m1[i * IN + 2 * jp + 1] != 0;
        WZ w;
        w.w.x = ma ? (mx ? (_Float16)-1.0f : (_Float16)1.0f) : (_Float16)0.0f;
        w.w.y = mb ? (mx ? (_Float16)-1.0f : (_Float16)1.0f) : (_Float16)0.0f;
        w.z.x = (!ma && !mx) ? (_Float16)1.0f : (_Float16)0.0f;
        w.z.y = (!mb && !mx) ? (_Float16)1.0f : (_Float16)0.0f;
        wz1[jp * HID + i] = w;
    } else {
        int e = idx - NXH - NW1;           // [jp<128][o<512]
        int o = e & (IN - 1);
        int jp = e >> 9;
        bool mx = rowmax(lg2, u2, o);
        bool ma = m2[o * HID + 2 * jp] != 0;
        bool mb = m2[o * HID + 2 * jp + 1] != 0;
        WZ w;
        w.w.x = ma ? (mx ? (_Float16)-1.0f : (_Float16)1.0f) : (_Float16)0.0f;
        w.w.y = mb ? (mx ? (_Float16)-1.0f : (_Float16)1.0f) : (_Float16)0.0f;
        w.z.x = (!ma && !mx) ? (_Float16)1.0f : (_Float16)0.0f;
        w.z.y = (!mb && !mx) ? (_Float16)1.0f : (_Float16)0.0f;
        wz2[jp * IN + o] = w;
    }
}

// One layer, full-J reduction, fp16 packed.
// Lanes span 64 output rows (coalesced WZ loads / output stores); wave-uniform
// batch rows -> x loads are scalar; b-tile=2 + 2-way jp unroll -> 4 min-chains.
// JP = number of j-pairs, OD = output rows.
template <int JP, int OD, bool OUTF32>
__global__ __launch_bounds__(256) void layer_kernel(
    const h2* __restrict__ xin,   // [B][JP] packed pairs
    const WZ* __restrict__ wzT,   // [JP][OD]
    const float* __restrict__ lg,
    const float* __restrict__ uu,
    void* __restrict__ outp)      // f32 [B][OD] or f16 [B][OD]
{
    constexpr int OT = OD / 64;
    int bx = blockIdx.x;
    int otile = bx % OT;
    int btile = bx / OT;           // B/8 batch tiles
    int lane = threadIdx.x & 63;
    int wv = __builtin_amdgcn_readfirstlane((int)(threadIdx.x >> 6));
    int o = otile * 64 + lane;
    int b0 = btile * 8 + wv * 2;

    bool mx = rowmax(lg, uu, o);
    _Float16 inis = mx ? (_Float16)0.0f : (_Float16)1.0f;
    h2 ini; ini.x = inis; ini.y = inis;
    h2 a0 = ini, a1 = ini, a2 = ini, a3 = ini;

    const WZ* wp = wzT + o;
    const h2* x0p = xin + (size_t)b0 * JP;
    const h2* x1p = xin + (size_t)(b0 + 1) * JP;

    for (int jp = 0; jp < JP; jp += 2) {
        WZ wa = wp[(size_t)jp * OD];
        WZ wb = wp[(size_t)(jp + 1) * OD];
        h2 xa0 = x0p[jp], xb0 = x0p[jp + 1];
        h2 xa1 = x1p[jp], xb1 = x1p[jp + 1];
        a0 = __builtin_elementwise_min(a0, wa.w * xa0 + wa.z);
        a1 = __builtin_elementwise_min(a1, wa.w * xa1 + wa.z);
        a2 = __builtin_elementwise_min(a2, wb.w * xb0 + wb.z);
        a3 = __builtin_elementwise_min(a3, wb.w * xb1 + wb.z);
    }
    a0 = __builtin_elementwise_min(a0, a2);
    a1 = __builtin_elementwise_min(a1, a3);
    float v0 = fminf((float)a0.x, (float)a0.y);
    float v1 = fminf((float)a1.x, (float)a1.y);
    if (mx) { v0 = -v0; v1 = -v1; }

    if (OUTF32) {
        float* out = (float*)outp;
        out[(size_t)b0 * OD + o] = v0;
        out[(size_t)(b0 + 1) * OD + o] = v1;
    } else {
        _Float16* out = (_Float16*)outp;
        out[(size_t)b0 * OD + o] = (_Float16)v0;
        out[(size_t)(b0 + 1) * OD + o] = (_Float16)v1;
    }
}

extern "C" void kernel_launch(void* const* d_in, const int* in_sizes, int n_in,
                              void* d_out, int out_size, void* d_ws, size_t ws_size,
                              hipStream_t stream)
{
    const float* x       = (const float*)d_in[0];  // (1024, 512)
    const float* logits1 = (const float*)d_in[1];  // (256, 2)
    const float* u1      = (const float*)d_in[2];  // (256, 2)
    const float* logits2 = (const float*)d_in[3];  // (512, 2)
    const float* u2      = (const float*)d_in[4];  // (512, 2)
    const int*   mask1   = (const int*)d_in[5];    // (256, 512)
    const int*   mask2   = (const int*)d_in[6];    // (512, 256)
    float* out = (float*)d_out;                    // (1024, 512) f32

    char* ws = (char*)d_ws;
    WZ* wz1 = (WZ*)(ws);                      // 512 KB: [256 jp][256 i]
    WZ* wz2 = (WZ*)(ws + (512 << 10));        // 512 KB: [128 jp][512 o]
    h2* xh  = (h2*)(ws + (1 << 20));          // 512 KB: [1024][256] packed x
    _Float16* hh = (_Float16*)(ws + 3 * (512 << 10)); // 512 KB: [1024][256] h (fp16)

    // 1) prep: 262144 + 65536 + 65536 threads = 1536 blocks
    prep_kernel<<<1536, 256, 0, stream>>>(x, logits1, u1, logits2, u2,
                                          mask1, mask2, wz1, wz2, xh);

    // 2) layer 1: JP=256, OD=256. Grid = 4 otiles * 128 btiles = 512 blocks.
    layer_kernel<256, 256, false><<<512, 256, 0, stream>>>(xh, wz1, logits1, u1, (void*)hh);

    // 3) layer 2: JP=128, OD=512. Grid = 8 * 128 = 1024 blocks.
    layer_kernel<128, 512, true><<<1024, 256, 0, stream>>>((const h2*)hh, wz2, logits2, u2, (void*)out);
}

// Round 4
// 101.029 us; speedup vs baseline: 1.0931x; 1.0222x over previous
//
#include <hip/hip_runtime.h>
#include <math.h>
#include <stdint.h>

constexpr int B = 1024;
constexpr int IN = 512;   // layer1 feature dim, layer2 output dim
constexpr int HID = 256;  // layer1 output dim, layer2 feature dim

typedef _Float16 h2 __attribute__((ext_vector_type(2)));

__device__ __forceinline__ h2 asb(uint32_t v) { return __builtin_bit_cast(h2, v); }
// llvm.minnum -> IEEE minNum: min(x, qNaN) = x. Codes rely on this.
__device__ __forceinline__ h2 pkmin(h2 a, h2 b) { return __builtin_elementwise_min(a, b); }

__device__ __forceinline__ float gscore(float l, float u) {
    float uc = fminf(fmaxf(u, 1e-10f), 1.0f);
    return l - logf(-logf(uc));
}
// true -> argmax index 1 -> "max" node (strict >, matches jnp.argmax tie->0)
__device__ __forceinline__ bool rowmax(const float* __restrict__ lg,
                                       const float* __restrict__ uu, int r) {
    return gscore(lg[2 * r + 1], uu[2 * r + 1]) > gscore(lg[2 * r], uu[2 * r]);
}

// Build: xh (x packed to f16 pairs), n-code tables, sign tables.
// Code per (row, j): masked -> rowsign (0x0000 min / 0x8000 max; x>=0 so x|0x8000 == -x),
// unmasked -> 0xFFFF (qNaN, ignored by minNum).
// n-table layout: [otile][jp2][lane]; one uint2 covers 4 consecutive j.
__global__ __launch_bounds__(256) void prep_kernel(
    const float* __restrict__ x,
    const float* __restrict__ lg1, const float* __restrict__ u1,
    const float* __restrict__ lg2, const float* __restrict__ u2,
    const int* __restrict__ m1, const int* __restrict__ m2,
    uint32_t* __restrict__ xh, uint2* __restrict__ n1, uint2* __restrict__ n2,
    uint16_t* __restrict__ sgn1, uint16_t* __restrict__ sgn2)
{
    int idx = blockIdx.x * 256 + threadIdx.x;
    constexpr int NXH = B * IN / 2;          // 262144
    constexpr int NN1 = (IN / 4) * HID;      // 32768: jp2 in [0,128), i in [0,256)
    if (idx < NXH) {
        float2 v = reinterpret_cast<const float2*>(x)[idx];
        h2 hv; hv.x = (_Float16)v.x; hv.y = (_Float16)v.y;
        xh[idx] = __builtin_bit_cast(uint32_t, hv);
    } else if (idx < NXH + NN1) {
        int e = idx - NXH;
        int i = e & (HID - 1);
        int jp2 = e >> 8;
        uint32_t s = rowmax(lg1, u1, i) ? 0x8000u : 0u;
        int4 mm = reinterpret_cast<const int4*>(m1 + (size_t)i * IN)[jp2]; // cols 4jp2..+3
        uint32_t c0 = mm.x ? s : 0xFFFFu;
        uint32_t c1 = mm.y ? s : 0xFFFFu;
        uint32_t c2 = mm.z ? s : 0xFFFFu;
        uint32_t c3 = mm.w ? s : 0xFFFFu;
        n1[(((i >> 6) * 128) + jp2) * 64 + (i & 63)] =
            make_uint2(c0 | (c1 << 16), c2 | (c3 << 16));
        if (jp2 == 0) sgn1[i] = (uint16_t)s;
    } else {
        int e = idx - NXH - NN1;             // jp2 in [0,64), o in [0,512)
        int o = e & (IN - 1);
        int jp2 = e >> 9;
        uint32_t s = rowmax(lg2, u2, o) ? 0x8000u : 0u;
        int4 mm = reinterpret_cast<const int4*>(m2 + (size_t)o * HID)[jp2];
        uint32_t c0 = mm.x ? s : 0xFFFFu;
        uint32_t c1 = mm.y ? s : 0xFFFFu;
        uint32_t c2 = mm.z ? s : 0xFFFFu;
        uint32_t c3 = mm.w ? s : 0xFFFFu;
        n2[(((o >> 6) * 64) + jp2) * 64 + (o & 63)] =
            make_uint2(c0 | (c1 << 16), c2 | (c3 << 16));
        if (jp2 == 0) sgn2[o] = (uint16_t)s;
    }
}

// One layer, full-J reduction. 256-thread blocks (known-good config), no LDS.
// Lanes span 64 output rows (coalesced n-loads/stores); each wave owns 2 batch
// rows (wave-uniform x addresses -> scalar-promotable); 4 independent
// min-chains per thread for ILP. JP2 = J/4 (uint2 n-steps), OD = output rows.
template <int JP2, int OD, bool OUTF32>
__global__ __launch_bounds__(256) void layer_kernel(
    const uint32_t* __restrict__ xin,  // [B][J/2] f16-pair words
    const uint2* __restrict__ nt,      // [OD/64][JP2][64]
    const uint16_t* __restrict__ sgn,  // [OD]
    void* __restrict__ outp)           // f16 [B][OD] or f32 [B][OD]
{
    constexpr int OT = OD / 64;
    constexpr int JW = JP2 / 2;        // uint4 x-steps (8 j each)
    int bx = blockIdx.x;
    int ot = bx % OT;
    int btile = bx / OT;               // B/8 tiles
    int tid = threadIdx.x;
    int lane = tid & 63;
    int wv = tid >> 6;
    int o = (ot << 6) + lane;
    int b0 = (btile << 3) + (wv << 1);

    uint32_t s = (uint32_t)sgn[o];
    uint32_t sini = s ? 0u : 0x3C003C00u;   // max-row -> 0.0 (negated dom), min-row -> 1.0
    h2 a00 = asb(sini), a01 = asb(sini), a10 = asb(sini), a11 = asb(sini);

    const uint2* np = nt + (size_t)ot * (JP2 * 64) + lane;
    const uint4* xr0 = (const uint4*)(xin + (size_t)b0 * (JP2 * 2));
    const uint4* xr1 = (const uint4*)(xin + (size_t)(b0 + 1) * (JP2 * 2));

#pragma unroll 4
    for (int jc = 0; jc < JW; ++jc) {
        uint4 x0 = xr0[jc];
        uint4 x1 = xr1[jc];
        uint2 na = np[(2 * jc) * 64];
        uint2 nb = np[(2 * jc + 1) * 64];
        a00 = pkmin(a00, asb(x0.x | na.x));
        a01 = pkmin(a01, asb(x0.y | na.y));
        a10 = pkmin(a10, asb(x1.x | na.x));
        a11 = pkmin(a11, asb(x1.y | na.y));
        a00 = pkmin(a00, asb(x0.z | nb.x));
        a01 = pkmin(a01, asb(x0.w | nb.y));
        a10 = pkmin(a10, asb(x1.z | nb.x));
        a11 = pkmin(a11, asb(x1.w | nb.y));
    }
    h2 c0 = pkmin(a00, a01);
    h2 c1 = pkmin(a10, a11);
    _Float16 r0 = c0.x < c0.y ? c0.x : c0.y;   // accumulators are never NaN
    _Float16 r1 = c1.x < c1.y ? c1.x : c1.y;
    uint16_t r0b = (uint16_t)(__builtin_bit_cast(uint16_t, r0) ^ (uint16_t)s);
    uint16_t r1b = (uint16_t)(__builtin_bit_cast(uint16_t, r1) ^ (uint16_t)s);
    if (OUTF32) {
        float* out = (float*)outp;
        out[(size_t)b0 * OD + o]       = (float)__builtin_bit_cast(_Float16, r0b);
        out[(size_t)(b0 + 1) * OD + o] = (float)__builtin_bit_cast(_Float16, r1b);
    } else {
        uint16_t* out = (uint16_t*)outp;
        out[(size_t)b0 * OD + o]       = r0b;
        out[(size_t)(b0 + 1) * OD + o] = r1b;
    }
}

extern "C" void kernel_launch(void* const* d_in, const int* in_sizes, int n_in,
                              void* d_out, int out_size, void* d_ws, size_t ws_size,
                              hipStream_t stream)
{
    const float* x       = (const float*)d_in[0];  // (1024, 512)
    const float* logits1 = (const float*)d_in[1];  // (256, 2)
    const float* u1      = (const float*)d_in[2];  // (256, 2)
    const float* logits2 = (const float*)d_in[3];  // (512, 2)
    const float* u2      = (const float*)d_in[4];  // (512, 2)
    const int*   mask1   = (const int*)d_in[5];    // (256, 512)
    const int*   mask2   = (const int*)d_in[6];    // (512, 256)
    float* out = (float*)d_out;                    // (1024, 512) f32

    char* ws = (char*)d_ws;
    uint32_t* xh   = (uint32_t*)(ws);                                    // 1 MB
    uint2*    n1   = (uint2*)(ws + (1 << 20));                           // 256 KB
    uint2*    n2   = (uint2*)(ws + (1 << 20) + (256 << 10));             // 256 KB
    uint16_t* sgn1 = (uint16_t*)(ws + (1 << 20) + (512 << 10));          // 512 B
    uint16_t* sgn2 = (uint16_t*)(ws + (1 << 20) + (512 << 10) + 4096);   // 1 KB
    uint32_t* hh   = (uint32_t*)(ws + (1 << 20) + (512 << 10) + 8192);   // 512 KB: h f16 [1024][256]

    // 1) prep: 262144 + 32768 + 32768 threads = 1280 blocks
    prep_kernel<<<1280, 256, 0, stream>>>(x, logits1, u1, logits2, u2,
                                          mask1, mask2, xh, n1, n2, sgn1, sgn2);

    // 2) layer 1: J=512 (JP2=128), OD=256. Grid = 4 otiles * 128 btiles = 512.
    layer_kernel<128, 256, false><<<512, 256, 0, stream>>>(xh, n1, sgn1, (void*)hh);

    // 3) layer 2: J=256 (JP2=64), OD=512. Grid = 8 * 128 = 1024.
    layer_kernel<64, 512, true><<<1024, 256, 0, stream>>>(hh, n2, sgn2, (void*)out);
}

// Round 5
// 93.183 us; speedup vs baseline: 1.1852x; 1.0842x over previous
//
#include <hip/hip_runtime.h>
#include <math.h>
#include <stdint.h>

constexpr int B = 1024;
constexpr int IN = 512;   // layer1 feature dim, layer2 output dim
constexpr int HID = 256;  // layer1 output dim, layer2 feature dim

typedef _Float16 h2 __attribute__((ext_vector_type(2)));

__device__ __forceinline__ h2 asb(uint32_t v) { return __builtin_bit_cast(h2, v); }
// llvm.minnum -> IEEE minNum: min(x, qNaN) = x. Codes rely on this.
__device__ __forceinline__ h2 pkmin(h2 a, h2 b) { return __builtin_elementwise_min(a, b); }

__device__ __forceinline__ float gscore(float l, float u) {
    float uc = fminf(fmaxf(u, 1e-10f), 1.0f);
    return l - logf(-logf(uc));
}
// true -> argmax index 1 -> "max" node (strict >, matches jnp.argmax tie->0)
__device__ __forceinline__ bool rowmax(const float* __restrict__ lg,
                                       const float* __restrict__ uu, int r) {
    return gscore(lg[2 * r + 1], uu[2 * r + 1]) > gscore(lg[2 * r], uu[2 * r]);
}

__device__ __forceinline__ uint32_t code2(int m_lo, int m_hi, uint32_t s) {
    return (m_lo ? s : 0xFFFFu) | ((m_hi ? s : 0xFFFFu) << 16);
}

// Build: xh (x packed to f16 pairs), n-code tables (uint4 = 8 j per entry),
// sign tables. Code per (row, j): masked -> rowsign (0x0000 min / 0x8000 max;
// x>=0 so x|0x8000 == -x exactly), unmasked -> 0xFFFF (qNaN, ignored by minNum).
// n layout: [ot][jc][lane] uint4, ot = row>>6, lane = row&63, jc = j>>3.
__global__ __launch_bounds__(256) void prep_kernel(
    const float* __restrict__ x,
    const float* __restrict__ lg1, const float* __restrict__ u1,
    const float* __restrict__ lg2, const float* __restrict__ u2,
    const int* __restrict__ m1, const int* __restrict__ m2,
    uint32_t* __restrict__ xh, uint4* __restrict__ n1, uint4* __restrict__ n2,
    uint16_t* __restrict__ sgn1, uint16_t* __restrict__ sgn2)
{
    int idx = blockIdx.x * 256 + threadIdx.x;
    constexpr int NXH = B * IN / 2;     // 262144
    constexpr int NN1 = HID * (IN / 8); // 16384: i in [0,256), jc in [0,64)
    if (idx < NXH) {
        float2 v = reinterpret_cast<const float2*>(x)[idx];
        h2 hv; hv.x = (_Float16)v.x; hv.y = (_Float16)v.y;
        xh[idx] = __builtin_bit_cast(uint32_t, hv);
    } else if (idx < NXH + NN1) {
        int e = idx - NXH;
        int i = e & (HID - 1);
        int jc = e >> 8;                 // 0..63
        uint32_t s = rowmax(lg1, u1, i) ? 0x8000u : 0u;
        const int4* mp = reinterpret_cast<const int4*>(m1 + (size_t)i * IN + 8 * jc);
        int4 ma = mp[0], mb = mp[1];
        uint4 n;
        n.x = code2(ma.x, ma.y, s);
        n.y = code2(ma.z, ma.w, s);
        n.z = code2(mb.x, mb.y, s);
        n.w = code2(mb.z, mb.w, s);
        n1[(((i >> 6) * 64) + jc) * 64 + (i & 63)] = n;
        if (jc == 0) sgn1[i] = (uint16_t)s;
    } else {
        int e = idx - NXH - NN1;         // o in [0,512), jc in [0,32)
        int o = e & (IN - 1);
        int jc = e >> 9;                 // 0..31
        uint32_t s = rowmax(lg2, u2, o) ? 0x8000u : 0u;
        const int4* mp = reinterpret_cast<const int4*>(m2 + (size_t)o * HID + 8 * jc);
        int4 ma = mp[0], mb = mp[1];
        uint4 n;
        n.x = code2(ma.x, ma.y, s);
        n.y = code2(ma.z, ma.w, s);
        n.z = code2(mb.x, mb.y, s);
        n.w = code2(mb.z, mb.w, s);
        n2[(((o >> 6) * 32) + jc) * 64 + (o & 63)] = n;
        if (jc == 0) sgn2[o] = (uint16_t)s;
    }
}

// One layer, full-J reduction. 256-thread blocks, no LDS.
// Lanes span 64 output rows (coalesced n-loads/stores); each wave owns 2 batch
// rows (wave-uniform x addresses); 4 independent min-chains per thread.
// JW = J/8 (uint4 steps), OD = output rows.
template <int JW, int OD, bool OUTF32>
__global__ __launch_bounds__(256) void layer_kernel(
    const uint32_t* __restrict__ xin,  // [B][J/2] f16-pair words
    const uint4* __restrict__ nt,      // [OD/64][JW][64]
    const uint16_t* __restrict__ sgn,  // [OD]
    void* __restrict__ outp)           // f16 [B][OD] or f32 [B][OD]
{
    constexpr int OT = OD / 64;
    int bx = blockIdx.x;
    int ot = bx % OT;
    int btile = bx / OT;               // B/8 tiles
    int tid = threadIdx.x;
    int lane = tid & 63;
    int wv = tid >> 6;
    int o = (ot << 6) + lane;
    int b0 = (btile << 3) + (wv << 1);

    uint32_t s = (uint32_t)sgn[o];
    uint32_t sini = s ? 0u : 0x3C003C00u;   // max-row -> 0.0 (negated dom), min-row -> 1.0
    h2 a00 = asb(sini), a01 = asb(sini), a10 = asb(sini), a11 = asb(sini);

    const uint4* np = nt + (size_t)ot * (JW * 64) + lane;
    const uint4* xr0 = (const uint4*)(xin + (size_t)b0 * (JW * 4));
    const uint4* xr1 = (const uint4*)(xin + (size_t)(b0 + 1) * (JW * 4));

#pragma unroll 4
    for (int jc = 0; jc < JW; ++jc) {
        uint4 n  = np[jc * 64];
        uint4 x0 = xr0[jc];
        uint4 x1 = xr1[jc];
        a00 = pkmin(a00, asb(x0.x | n.x));
        a01 = pkmin(a01, asb(x0.y | n.y));
        a10 = pkmin(a10, asb(x1.x | n.x));
        a11 = pkmin(a11, asb(x1.y | n.y));
        a00 = pkmin(a00, asb(x0.z | n.z));
        a01 = pkmin(a01, asb(x0.w | n.w));
        a10 = pkmin(a10, asb(x1.z | n.z));
        a11 = pkmin(a11, asb(x1.w | n.w));
    }
    h2 c0 = pkmin(a00, a01);
    h2 c1 = pkmin(a10, a11);
    _Float16 r0 = c0.x < c0.y ? c0.x : c0.y;   // accumulators are never NaN
    _Float16 r1 = c1.x < c1.y ? c1.x : c1.y;
    uint16_t r0b = (uint16_t)(__builtin_bit_cast(uint16_t, r0) ^ (uint16_t)s);
    uint16_t r1b = (uint16_t)(__builtin_bit_cast(uint16_t, r1) ^ (uint16_t)s);
    if (OUTF32) {
        float* out = (float*)outp;
        out[(size_t)b0 * OD + o]       = (float)__builtin_bit_cast(_Float16, r0b);
        out[(size_t)(b0 + 1) * OD + o] = (float)__builtin_bit_cast(_Float16, r1b);
    } else {
        uint16_t* out = (uint16_t*)outp;
        out[(size_t)b0 * OD + o]       = r0b;
        out[(size_t)(b0 + 1) * OD + o] = r1b;
    }
}

extern "C" void kernel_launch(void* const* d_in, const int* in_sizes, int n_in,
                              void* d_out, int out_size, void* d_ws, size_t ws_size,
                              hipStream_t stream)
{
    const float* x       = (const float*)d_in[0];  // (1024, 512)
    const float* logits1 = (const float*)d_in[1];  // (256, 2)
    const float* u1      = (const float*)d_in[2];  // (256, 2)
    const float* logits2 = (const float*)d_in[3];  // (512, 2)
    const float* u2      = (const float*)d_in[4];  // (512, 2)
    const int*   mask1   = (const int*)d_in[5];    // (256, 512)
    const int*   mask2   = (const int*)d_in[6];    // (512, 256)
    float* out = (float*)d_out;                    // (1024, 512) f32

    char* ws = (char*)d_ws;
    uint32_t* xh   = (uint32_t*)(ws);                                    // 1 MB
    uint4*    n1   = (uint4*)(ws + (1 << 20));                           // 256 KB
    uint4*    n2   = (uint4*)(ws + (1 << 20) + (256 << 10));             // 256 KB
    uint16_t* sgn1 = (uint16_t*)(ws + (1 << 20) + (512 << 10));          // 512 B
    uint16_t* sgn2 = (uint16_t*)(ws + (1 << 20) + (512 << 10) + 4096);   // 1 KB
    uint32_t* hh   = (uint32_t*)(ws + (1 << 20) + (512 << 10) + 8192);   // 512 KB: h f16 [1024][256]

    // 1) prep: 262144 + 16384 + 16384 threads = 1152 blocks
    prep_kernel<<<1152, 256, 0, stream>>>(x, logits1, u1, logits2, u2,
                                          mask1, mask2, xh, n1, n2, sgn1, sgn2);

    // 2) layer 1: J=512 (JW=64), OD=256. Grid = 4 otiles * 128 btiles = 512.
    layer_kernel<64, 256, false><<<512, 256, 0, stream>>>(xh, n1, sgn1, (void*)hh);

    // 3) layer 2: J=256 (JW=32), OD=512. Grid = 8 * 128 = 1024.
    layer_kernel<32, 512, true><<<1024, 256, 0, stream>>>(hh, n2, sgn2, (void*)out);
}

// Round 6
// 88.835 us; speedup vs baseline: 1.2432x; 1.0489x over previous
//
#include <hip/hip_runtime.h>
#include <math.h>
#include <stdint.h>

constexpr int B = 1024;
constexpr int IN = 512;   // layer1 feature dim, layer2 output dim
constexpr int HID = 256;  // layer1 output dim, layer2 feature dim

typedef _Float16 h2 __attribute__((ext_vector_type(2)));

__device__ __forceinline__ h2 asb(uint32_t v) { return __builtin_bit_cast(h2, v); }
// llvm.minnum -> IEEE minNum: min(x, qNaN) = x. Codes rely on this.
__device__ __forceinline__ h2 pkmin(h2 a, h2 b) { return __builtin_elementwise_min(a, b); }

__device__ __forceinline__ float gscore(float l, float u) {
    float uc = fminf(fmaxf(u, 1e-10f), 1.0f);
    return l - logf(-logf(uc));
}
// true -> argmax index 1 -> "max" node (strict >, matches jnp.argmax tie->0)
__device__ __forceinline__ bool rowmax(const float* __restrict__ lg,
                                       const float* __restrict__ uu, int r) {
    return gscore(lg[2 * r + 1], uu[2 * r + 1]) > gscore(lg[2 * r], uu[2 * r]);
}

__device__ __forceinline__ uint32_t code2(int m_lo, int m_hi, uint32_t s) {
    return (m_lo ? s : 0xFFFFu) | ((m_hi ? s : 0xFFFFu) << 16);
}

// Build: xh (x packed to f16 pairs), n-code tables (uint4 = 8 j per entry),
// sign tables. Code per (row, j): masked -> rowsign (0x0000 min / 0x8000 max;
// x>=0 so x|0x8000 == -x exactly), unmasked -> 0xFFFF (qNaN, ignored by minNum).
// n layout: [ot][jc][lane] uint4, ot = row>>6, lane = row&63, jc = j>>3.
__global__ __launch_bounds__(256) void prep_kernel(
    const float* __restrict__ x,
    const float* __restrict__ lg1, const float* __restrict__ u1,
    const float* __restrict__ lg2, const float* __restrict__ u2,
    const int* __restrict__ m1, const int* __restrict__ m2,
    uint32_t* __restrict__ xh, uint4* __restrict__ n1, uint4* __restrict__ n2,
    uint16_t* __restrict__ sgn1, uint16_t* __restrict__ sgn2)
{
    int idx = blockIdx.x * 256 + threadIdx.x;
    constexpr int NXH = B * IN / 2;     // 262144
    constexpr int NN1 = HID * (IN / 8); // 16384: i in [0,256), jc in [0,64)
    if (idx < NXH) {
        float2 v = reinterpret_cast<const float2*>(x)[idx];
        h2 hv; hv.x = (_Float16)v.x; hv.y = (_Float16)v.y;
        xh[idx] = __builtin_bit_cast(uint32_t, hv);
    } else if (idx < NXH + NN1) {
        int e = idx - NXH;
        int i = e & (HID - 1);
        int jc = e >> 8;                 // 0..63
        uint32_t s = rowmax(lg1, u1, i) ? 0x8000u : 0u;
        const int4* mp = reinterpret_cast<const int4*>(m1 + (size_t)i * IN + 8 * jc);
        int4 ma = mp[0], mb = mp[1];
        uint4 n;
        n.x = code2(ma.x, ma.y, s);
        n.y = code2(ma.z, ma.w, s);
        n.z = code2(mb.x, mb.y, s);
        n.w = code2(mb.z, mb.w, s);
        n1[(((i >> 6) * 64) + jc) * 64 + (i & 63)] = n;
        if (jc == 0) sgn1[i] = (uint16_t)s;
    } else {
        int e = idx - NXH - NN1;         // o in [0,512), jc in [0,32)
        int o = e & (IN - 1);
        int jc = e >> 9;                 // 0..31
        uint32_t s = rowmax(lg2, u2, o) ? 0x8000u : 0u;
        const int4* mp = reinterpret_cast<const int4*>(m2 + (size_t)o * HID + 8 * jc);
        int4 ma = mp[0], mb = mp[1];
        uint4 n;
        n.x = code2(ma.x, ma.y, s);
        n.y = code2(ma.z, ma.w, s);
        n.z = code2(mb.x, mb.y, s);
        n.w = code2(mb.z, mb.w, s);
        n2[(((o >> 6) * 32) + jc) * 64 + (o & 63)] = n;
        if (jc == 0) sgn2[o] = (uint16_t)s;
    }
}

// One layer, full-J reduction. 256-thread blocks, no LDS.
// Lanes span 64 output rows (coalesced n-loads/stores). Each wave owns 2 batch
// rows; the wave id is readfirstlane'd so b0 is compiler-provably uniform ->
// x-row loads become s_load_dwordx4 on the scalar pipe (inner loop: 1 VMEM +
// 2 SMEM + 16 VALU per 32 elements). 4 independent min-chains per thread.
// JW = J/8 (uint4 steps), OD = output rows.
template <int JW, int OD, bool OUTF32>
__global__ __launch_bounds__(256) void layer_kernel(
    const uint32_t* __restrict__ xin,  // [B][J/2] f16-pair words
    const uint4* __restrict__ nt,      // [OD/64][JW][64]
    const uint16_t* __restrict__ sgn,  // [OD]
    void* __restrict__ outp)           // f16 [B][OD] or f32 [B][OD]
{
    constexpr int OT = OD / 64;
    int bx = blockIdx.x;
    int ot = bx % OT;
    int btile = bx / OT;               // B/8 tiles
    int tid = threadIdx.x;
    int lane = tid & 63;
    int wv = __builtin_amdgcn_readfirstlane(tid >> 6);  // uniform wave id
    int o = (ot << 6) + lane;
    int b0 = (btile << 3) + (wv << 1); // uniform batch-row base

    uint32_t s = (uint32_t)sgn[o];
    uint32_t sini = s ? 0u : 0x3C003C00u;   // max-row -> 0.0 (negated dom), min-row -> 1.0
    h2 a00 = asb(sini), a01 = asb(sini), a10 = asb(sini), a11 = asb(sini);

    const uint4* np = nt + (size_t)ot * (JW * 64) + lane;
    const uint4* xr0 = (const uint4*)(xin + (size_t)b0 * (JW * 4));  // uniform
    const uint4* xr1 = xr0 + JW;                                     // next row

#pragma unroll 8
    for (int jc = 0; jc < JW; ++jc) {
        uint4 n  = np[jc * 64];
        uint4 x0 = xr0[jc];
        uint4 x1 = xr1[jc];
        a00 = pkmin(a00, asb(x0.x | n.x));
        a01 = pkmin(a01, asb(x0.y | n.y));
        a10 = pkmin(a10, asb(x1.x | n.x));
        a11 = pkmin(a11, asb(x1.y | n.y));
        a00 = pkmin(a00, asb(x0.z | n.z));
        a01 = pkmin(a01, asb(x0.w | n.w));
        a10 = pkmin(a10, asb(x1.z | n.z));
        a11 = pkmin(a11, asb(x1.w | n.w));
    }
    h2 c0 = pkmin(a00, a01);
    h2 c1 = pkmin(a10, a11);
    _Float16 r0 = c0.x < c0.y ? c0.x : c0.y;   // accumulators are never NaN
    _Float16 r1 = c1.x < c1.y ? c1.x : c1.y;
    uint16_t r0b = (uint16_t)(__builtin_bit_cast(uint16_t, r0) ^ (uint16_t)s);
    uint16_t r1b = (uint16_t)(__builtin_bit_cast(uint16_t, r1) ^ (uint16_t)s);
    if (OUTF32) {
        float* out = (float*)outp;
        out[(size_t)b0 * OD + o]       = (float)__builtin_bit_cast(_Float16, r0b);
        out[(size_t)(b0 + 1) * OD + o] = (float)__builtin_bit_cast(_Float16, r1b);
    } else {
        uint16_t* out = (uint16_t*)outp;
        out[(size_t)b0 * OD + o]       = r0b;
        out[(size_t)(b0 + 1) * OD + o] = r1b;
    }
}

extern "C" void kernel_launch(void* const* d_in, const int* in_sizes, int n_in,
                              void* d_out, int out_size, void* d_ws, size_t ws_size,
                              hipStream_t stream)
{
    const float* x       = (const float*)d_in[0];  // (1024, 512)
    const float* logits1 = (const float*)d_in[1];  // (256, 2)
    const float* u1      = (const float*)d_in[2];  // (256, 2)
    const float* logits2 = (const float*)d_in[3];  // (512, 2)
    const float* u2      = (const float*)d_in[4];  // (512, 2)
    const int*   mask1   = (const int*)d_in[5];    // (256, 512)
    const int*   mask2   = (const int*)d_in[6];    // (512, 256)
    float* out = (float*)d_out;                    // (1024, 512) f32

    char* ws = (char*)d_ws;
    uint32_t* xh   = (uint32_t*)(ws);                                    // 1 MB
    uint4*    n1   = (uint4*)(ws + (1 << 20));                           // 256 KB
    uint4*    n2   = (uint4*)(ws + (1 << 20) + (256 << 10));             // 256 KB
    uint16_t* sgn1 = (uint16_t*)(ws + (1 << 20) + (512 << 10));          // 512 B
    uint16_t* sgn2 = (uint16_t*)(ws + (1 << 20) + (512 << 10) + 4096);   // 1 KB
    uint32_t* hh   = (uint32_t*)(ws + (1 << 20) + (512 << 10) + 8192);   // 512 KB: h f16 [1024][256]

    // 1) prep: 262144 + 16384 + 16384 threads = 1152 blocks
    prep_kernel<<<1152, 256, 0, stream>>>(x, logits1, u1, logits2, u2,
                                          mask1, mask2, xh, n1, n2, sgn1, sgn2);

    // 2) layer 1: J=512 (JW=64), OD=256. Grid = 4 otiles * 128 btiles = 512.
    layer_kernel<64, 256, false><<<512, 256, 0, stream>>>(xh, n1, sgn1, (void*)hh);

    // 3) layer 2: J=256 (JW=32), OD=512. Grid = 8 * 128 = 1024.
    layer_kernel<32, 512, true><<<1024, 256, 0, stream>>>(hh, n2, sgn2, (void*)out);
}